// Round 11
// baseline (157.003 us; speedup 1.0000x reference)
//
#include <hip/hip_runtime.h>
#include <hip/hip_fp16.h>

#define BSZ   1024
#define INDIM 768
#define PROJ  9216     // 256*6*6
#define NCAP  512
#define NCLS  5
#define K2    2304     // conv GEMM K = 9 taps * 256 ic

typedef __bf16    bf16x8 __attribute__((ext_vector_type(8)));
typedef _Float16  f16x8  __attribute__((ext_vector_type(8)));
typedef float     f32x4  __attribute__((ext_vector_type(4)));
typedef _Float16  h2     __attribute__((ext_vector_type(2)));

static __device__ __forceinline__ unsigned short f2bf(float f) {
  unsigned int x = __float_as_uint(f);
  return (unsigned short)((x + 0x7fffu + ((x >> 16) & 1u)) >> 16);
}
static __device__ __forceinline__ float bf2f(unsigned int u) {
  return __uint_as_float(u << 16);
}
static __device__ __forceinline__ unsigned short f2h(float f) {
  return __builtin_bit_cast(unsigned short, (_Float16)f);
}

#if defined(__has_builtin)
#if __has_builtin(__builtin_amdgcn_fdot2)
#define HAVE_FDOT2 1
#endif
#endif
static __device__ __forceinline__ float fdot2(h2 a, h2 b, float c) {
#ifdef HAVE_FDOT2
  return __builtin_amdgcn_fdot2(a, b, c, false);
#else
  return c + (float)a[0] * (float)b[0] + (float)a[1] * (float)b[1];
#endif
}
static __device__ __forceinline__ h2 u2h2(unsigned int u) {
  return __builtin_bit_cast(h2, u);
}

// global -> LDS direct (16B per lane)
static __device__ __forceinline__ void gload16(const void* g, void* l) {
  auto gp = reinterpret_cast<const unsigned int __attribute__((address_space(1)))*>(
      (unsigned long long)g);
  auto lp = reinterpret_cast<unsigned int __attribute__((address_space(3)))*>(
      (unsigned long long)l);
  __builtin_amdgcn_global_load_lds(gp, lp, 16, 0, 0);
}

// =====================================================================
// mfma_gemm_bk64: 128x128 tile, BK=64 -> 32 MFMA per barrier pair.
// C[M][N] = relu(A[M][K] * Bt[N][K]^T + bias), bf16 out. 4 waves (2x2).
// LDS 64 KB double-buffered; XOR swizzle seg^(row&7) on 16B segs.
// =====================================================================
__global__ __launch_bounds__(256) void mfma_gemm_bk64(
    const unsigned short* __restrict__ A,   // [M][K] bf16
    const unsigned short* __restrict__ Bt,  // [N][K] bf16
    const float* __restrict__ bias,         // [N]
    unsigned short* __restrict__ Cout,      // [M][N] bf16
    int M, int N, int K) {
  __shared__ __align__(16) unsigned short smem[32768];  // 2 x (A 8192 + B 8192)
  const int t    = threadIdx.x;
  const int bn   = blockIdx.x * 128;
  const int bm   = blockIdx.y * 128;
  const int lane = t & 63, wid = t >> 6;
  const int wm   = (wid >> 1) * 64;
  const int wn   = (wid & 1) * 64;
  const int l15  = lane & 15, kb = lane >> 4;

  // staging: A/B each 1024 chunks of 16B; thread stages 4 of each
  const unsigned short* asrc[4];
  const unsigned short* bsrc[4];
#pragma unroll
  for (int cc = 0; cc < 4; ++cc) {
    const int c = t + cc * 256;
    const int row = c >> 3, seg = c & 7;
    const int sk = (seg ^ (row & 7)) << 3;
    asrc[cc] = A  + (size_t)(bm + row) * K + sk;
    bsrc[cc] = Bt + (size_t)(bn + row) * K + sk;
  }

  int aoff[4][2], boff[4][2];
#pragma unroll
  for (int i = 0; i < 4; ++i)
#pragma unroll
    for (int kk = 0; kk < 2; ++kk) {
      const int ra = wm + i * 16 + l15, sa = kk * 4 + kb;
      aoff[i][kk] = ra * 64 + ((sa ^ (ra & 7)) << 3);
      const int rb = wn + i * 16 + l15;
      boff[i][kk] = 8192 + rb * 64 + ((sa ^ (rb & 7)) << 3);
    }

  f32x4 acc[4][4];
#pragma unroll
  for (int i = 0; i < 4; ++i)
#pragma unroll
    for (int j = 0; j < 4; ++j)
#pragma unroll
      for (int q = 0; q < 4; ++q) acc[i][j][q] = 0.f;

  const int nk = K >> 6;
  auto stage = [&](int ks, int buf) {
    const int ko = ks << 6;
    unsigned short* sb = &smem[buf * 16384];
#pragma unroll
    for (int cc = 0; cc < 4; ++cc) {
      gload16(asrc[cc] + ko, sb + (t + cc * 256) * 8);
      gload16(bsrc[cc] + ko, sb + 8192 + (t + cc * 256) * 8);
    }
  };

  stage(0, 0);
  __syncthreads();

  int buf = 0;
  for (int ks = 0; ks < nk; ++ks) {
    if (ks + 1 < nk) stage(ks + 1, buf ^ 1);
    const unsigned short* base = &smem[buf * 16384];
    bf16x8 af[4][2], bfr[4][2];
#pragma unroll
    for (int i = 0; i < 4; ++i)
#pragma unroll
      for (int kk = 0; kk < 2; ++kk) {
        af[i][kk]  = *(const bf16x8*)(base + aoff[i][kk]);
        bfr[i][kk] = *(const bf16x8*)(base + boff[i][kk]);
      }
#pragma unroll
    for (int kk = 0; kk < 2; ++kk)
#pragma unroll
      for (int i = 0; i < 4; ++i)
#pragma unroll
        for (int j = 0; j < 4; ++j)
          acc[i][j] = __builtin_amdgcn_mfma_f32_16x16x32_bf16(af[i][kk], bfr[j][kk], acc[i][j], 0, 0, 0);
    __syncthreads();
    buf ^= 1;
  }

#pragma unroll
  for (int j = 0; j < 4; ++j) {
    const int col = bn + wn + j * 16 + l15;
    const float bv = bias[col];
#pragma unroll
    for (int i = 0; i < 4; ++i)
#pragma unroll
      for (int q = 0; q < 4; ++q) {
        const int row = bm + wm + i * 16 + kb * 4 + q;
        Cout[(size_t)row * N + col] = f2bf(fmaxf(acc[i][j][q] + bv, 0.f));
      }
  }
}

// =====================================================================
// conv_gemm_sq128: implicit-im2col conv GEMM, 128x128 tile, BK=64,
// fused squash epilogue writing u fp16. grid (2, 128) = 256 blocks.
// =====================================================================
__global__ __launch_bounds__(256) void conv_gemm_sq128(
    const unsigned short* __restrict__ ht,   // [1024][36][256] bf16
    const unsigned short* __restrict__ Wt2,  // [256][2304] bf16
    const float* __restrict__ convB,         // [256]
    unsigned short* __restrict__ U) {        // [1024][32][16][8] fp16
  __shared__ __align__(16) unsigned short smem[32768];
  const int t    = threadIdx.x;
  const int bn   = blockIdx.x * 128;
  const int bm   = blockIdx.y * 128;
  const int lane = t & 63, wid = t >> 6;
  const int wm   = (wid >> 1) * 64;
  const int wn   = (wid & 1) * 64;
  const int l15  = lane & 15, kb = lane >> 4;

  // A: gathered from ht; per chunk row the base points at (b, spb, swizzled ic seg)
  const unsigned short* asrc[4];
  const unsigned short* bsrc[4];
#pragma unroll
  for (int cc = 0; cc < 4; ++cc) {
    const int c = t + cc * 256;
    const int row = c >> 3, seg = c & 7;
    const int gr = bm + row, b = gr >> 4, p = gr & 15;
    const int spb = (p >> 2) * 6 + (p & 3);
    asrc[cc] = ht + (size_t)b * PROJ + spb * 256 + ((seg ^ (row & 7)) << 3);
    bsrc[cc] = Wt2 + (size_t)(bn + row) * K2 + ((seg ^ (row & 7)) << 3);
  }

  int aoff[4][2], boff[4][2];
#pragma unroll
  for (int i = 0; i < 4; ++i)
#pragma unroll
    for (int kk = 0; kk < 2; ++kk) {
      const int ra = wm + i * 16 + l15, sa = kk * 4 + kb;
      aoff[i][kk] = ra * 64 + ((sa ^ (ra & 7)) << 3);
      const int rb = wn + i * 16 + l15;
      boff[i][kk] = 8192 + rb * 64 + ((sa ^ (rb & 7)) << 3);
    }

  f32x4 acc[4][4];
#pragma unroll
  for (int i = 0; i < 4; ++i)
#pragma unroll
    for (int j = 0; j < 4; ++j)
#pragma unroll
      for (int q = 0; q < 4; ++q) acc[i][j][q] = 0.f;

  auto stage = [&](int ks, int buf) {
    const int tap  = ks >> 2;                       // 36 steps, 4 per tap
    const int aofs = (tap + 3 * (tap / 3)) * 256 + ((ks & 3) << 6);
    const int bofs = ks << 6;
    unsigned short* sb = &smem[buf * 16384];
#pragma unroll
    for (int cc = 0; cc < 4; ++cc) {
      gload16(asrc[cc] + aofs, sb + (t + cc * 256) * 8);
      gload16(bsrc[cc] + bofs, sb + 8192 + (t + cc * 256) * 8);
    }
  };

  stage(0, 0);
  __syncthreads();

  int buf = 0;
  for (int ks = 0; ks < 36; ++ks) {
    if (ks + 1 < 36) stage(ks + 1, buf ^ 1);
    const unsigned short* base = &smem[buf * 16384];
    bf16x8 af[4][2], bfr[4][2];
#pragma unroll
    for (int i = 0; i < 4; ++i)
#pragma unroll
      for (int kk = 0; kk < 2; ++kk) {
        af[i][kk]  = *(const bf16x8*)(base + aoff[i][kk]);
        bfr[i][kk] = *(const bf16x8*)(base + boff[i][kk]);
      }
#pragma unroll
    for (int kk = 0; kk < 2; ++kk)
#pragma unroll
      for (int i = 0; i < 4; ++i)
#pragma unroll
        for (int j = 0; j < 4; ++j)
          acc[i][j] = __builtin_amdgcn_mfma_f32_16x16x32_bf16(af[i][kk], bfr[j][kk], acc[i][j], 0, 0, 0);
    __syncthreads();
    buf ^= 1;
  }

  // epilogue: bias + per-capsule squash (8 consecutive l15 lanes) + u write
#pragma unroll
  for (int j = 0; j < 4; ++j) {
    const int oc  = bn + wn + j * 16 + l15;
    const int cap = oc >> 3, ii = oc & 7;
    const float bv = convB[oc];
#pragma unroll
    for (int i = 0; i < 4; ++i)
#pragma unroll
      for (int q = 0; q < 4; ++q) {
        const int row = bm + wm + i * 16 + kb * 4 + q;
        const int b = row >> 4, p = row & 15;
        const float val = acc[i][j][q] + bv;
        float sq = val * val;
        sq += __shfl_xor(sq, 1);
        sq += __shfl_xor(sq, 2);
        sq += __shfl_xor(sq, 4);
        const float scale = sq / (1.f + sq) / sqrtf(sq + 1e-8f);
        U[(size_t)b * 4096 + cap * 128 + p * 8 + ii] = f2h(val * scale);
      }
  }
}

// =====================================================================
// Transforms (unchanged — passing)
// =====================================================================
#define NX_ITEMS (BSZ * INDIM / 4)      // 196608
#define NW_ITEMS (NCAP * 640 / 4)       // 81920
#define NC_ITEMS 65536
#define NB_ITEMS PROJ                   // 9216
#define PREP_TOTAL (NX_ITEMS + NW_ITEMS + NC_ITEMS + NB_ITEMS)

__global__ __launch_bounds__(256) void prep_small(
    const float* __restrict__ x, unsigned short* __restrict__ xb,
    const float* __restrict__ Wr, __half2* __restrict__ wrh,
    const float* __restrict__ convW, unsigned short* __restrict__ wt2,
    const float* __restrict__ b1, float* __restrict__ pb1) {
  const int id = blockIdx.x * 256 + threadIdx.x;
  if (id < NX_ITEMS) {
    float4 v = ((const float4*)x)[id];
    ushort4 o;
    o.x = f2bf(v.x); o.y = f2bf(v.y); o.z = f2bf(v.z); o.w = f2bf(v.w);
    ((ushort4*)xb)[id] = o;
  } else if (id < NX_ITEMS + NW_ITEMS) {
    const int i = id - NX_ITEMS;
    float4 v = ((const float4*)Wr)[i];
    wrh[i * 2]     = __floats2half2_rn(v.x, v.y);
    wrh[i * 2 + 1] = __floats2half2_rn(v.z, v.w);
  } else if (id < NX_ITEMS + NW_ITEMS + NC_ITEMS) {
    const int i = id - NX_ITEMS - NW_ITEMS;
    const int oc = i >> 8, ic = i & 255;
    const float* s = convW + (size_t)i * 9;
#pragma unroll
    for (int tap = 0; tap < 9; ++tap)
      wt2[(size_t)oc * K2 + tap * 256 + ic] = f2bf(s[tap]);
  } else if (id < PREP_TOTAL) {
    const int n = id - NX_ITEMS - NW_ITEMS - NC_ITEMS;
    pb1[(n % 36) * 256 + n / 36] = b1[n];
  }
}

__global__ __launch_bounds__(256) void transpose_w1_perm(const float* __restrict__ W,
                                                         unsigned short* __restrict__ Wt) {
  __shared__ float tile[32][33];
  const int n0 = blockIdx.x * 32, k0 = blockIdx.y * 32;
  const int r = threadIdx.x >> 3, c = (threadIdx.x & 7) * 4;
  float4 v = *(const float4*)(W + (size_t)(k0 + r) * PROJ + n0 + c);
  tile[r][c] = v.x; tile[r][c + 1] = v.y; tile[r][c + 2] = v.z; tile[r][c + 3] = v.w;
  __syncthreads();
  ushort4 o;
  o.x = f2bf(tile[c + 0][r]); o.y = f2bf(tile[c + 1][r]);
  o.z = f2bf(tile[c + 2][r]); o.w = f2bf(tile[c + 3][r]);
  const int nn = n0 + r;
  const int prow = (nn % 36) * 256 + nn / 36;
  *(ushort4*)(Wt + (size_t)prow * INDIM + k0 + c) = o;
}

// =====================================================================
// uhat_gemm (R8 verbatim — passing, measured fast)
// =====================================================================
__global__ __launch_bounds__(512) void uhat_gemm(
    const unsigned short* __restrict__ U,    // [1024][512][8] fp16
    const unsigned short* __restrict__ Wrh,  // [512][80][8] fp16
    unsigned short* __restrict__ uhat,       // [CB][512][80] fp16
    float* __restrict__ s0q,                 // [8][CB][80]
    int b0, int CB) {
  __shared__ float sred[8][16][80];  // 40 KB
  const int mt = blockIdx.x, q = blockIdx.y;   // q 0..7
  const int t = threadIdx.x, wid = t >> 6, lane = t & 63;
  const int l15 = lane & 15, kb = lane >> 4;
  const int bm = mt * 16;
  const int gb = b0 + bm;

  f32x4 sacc[5];
#pragma unroll
  for (int j = 0; j < 5; ++j)
#pragma unroll
    for (int r = 0; r < 4; ++r) sacc[j][r] = 0.f;

  const uint4 zz = make_uint4(0, 0, 0, 0);
#pragma unroll
  for (int i = 0; i < 8; ++i) {
    const int n = q * 64 + wid * 8 + i;
    uint4 av = zz;
    if (kb == 0) av = *(const uint4*)(U + (size_t)(gb + l15) * 4096 + n * 8);
    const f16x8 uf = __builtin_bit_cast(f16x8, av);
#pragma unroll
    for (int jn = 0; jn < 5; ++jn) {
      uint4 wv = zz;
      if (kb == 0) wv = *(const uint4*)(Wrh + (size_t)n * 640 + (jn * 16 + l15) * 8);
      f32x4 z;
      z[0] = 0.f; z[1] = 0.f; z[2] = 0.f; z[3] = 0.f;
      f32x4 c = __builtin_amdgcn_mfma_f32_16x16x32_f16(
          __builtin_bit_cast(f16x8, wv), uf, z, 0, 0, 0);
      ushort4 st;
      st.x = f2h(c[0]); st.y = f2h(c[1]); st.z = f2h(c[2]); st.w = f2h(c[3]);
      *(ushort4*)(uhat + ((size_t)(bm + l15) * 512 + n) * 80 + jn * 16 + kb * 4) = st;
#pragma unroll
      for (int qq = 0; qq < 4; ++qq) sacc[jn][qq] += c[qq];
    }
  }

#pragma unroll
  for (int jn = 0; jn < 5; ++jn)
#pragma unroll
    for (int qq = 0; qq < 4; ++qq)
      sred[wid][l15][jn * 16 + kb * 4 + qq] = sacc[jn][qq];
  __syncthreads();
#pragma unroll
  for (int k = 0; k < 3; ++k) {
    const int id = t + k * 512;
    if (id < 1280) {
      const int bb = id / 80, od = id % 80;
      float val = 0.f;
#pragma unroll
      for (int w = 0; w < 8; ++w) val += sred[w][bb][od];
      s0q[((size_t)q * CB + bm + bb) * 80 + od] = val;
    }
  }
}

// =====================================================================
// route_pass<MODE> (R8 verbatim — passing)
// =====================================================================
template <int MODE>
__global__ __launch_bounds__(256) void route_pass(
    const unsigned short* __restrict__ uhat,  // [CB][512][80] fp16
    const float* __restrict__ s0q,            // [8][CB][80] (MODE 1)
    const float* __restrict__ vsum_in,        // [CB][80] (MODE 2)
    float* __restrict__ vsum_out,             // [CB][80] (MODE 1)
    float* __restrict__ out,                  // final outputs (MODE 2)
    int b0, int CB) {
  __shared__ unsigned int vph2[40];
  __shared__ float red[4][2][40];
  const int bl = blockIdx.x;
  const int b  = b0 + bl;
  const int t  = threadIdx.x;

  float v0r = 0.f;
  if (t < 80) {
    if (MODE == 1) {
      float s = 0.f;
#pragma unroll
      for (int g = 0; g < 8; ++g) s += s0q[((size_t)g * CB + bl) * 80 + t];
      s *= 0.2f;
      float sq = s * s;
      sq += __shfl_xor(sq, 1);
      sq += __shfl_xor(sq, 2);
      sq += __shfl_xor(sq, 4);
      sq += __shfl_xor(sq, 8);
      const float scale = sq / (1.f + sq) / sqrtf(sq + 1e-8f);
      v0r = s * scale;
    } else {
      v0r = vsum_in[(size_t)bl * 80 + t];
    }
    const float vnext = __shfl_down(v0r, 1);
    if ((t & 1) == 0)
      vph2[t >> 1] = __builtin_bit_cast(unsigned int, __floats2half2_rn(v0r, vnext));
  }
  __syncthreads();

  const int p = t >> 1, h = t & 1;
  float acc[5][8];
#pragma unroll
  for (int o = 0; o < 5; ++o)
#pragma unroll
    for (int j = 0; j < 8; ++j) acc[o][j] = 0.f;

  const unsigned short* ub = uhat + (size_t)bl * 40960;
  for (int c4 = 0; c4 < 4; ++c4) {
    const int n = c4 * 128 + p;
    const unsigned short* row = ub + n * 80 + h * 8;
    uint4 uv[5];
#pragma unroll
    for (int o = 0; o < 5; ++o) uv[o] = *(const uint4*)(row + o * 16);
    float ap[5];
#pragma unroll
    for (int o = 0; o < 5; ++o) {
      const int vb = o * 8 + h * 4;
      float a = fdot2(u2h2(uv[o].x), u2h2(vph2[vb]), 0.f);
      a = fdot2(u2h2(uv[o].y), u2h2(vph2[vb + 1]), a);
      a = fdot2(u2h2(uv[o].z), u2h2(vph2[vb + 2]), a);
      a = fdot2(u2h2(uv[o].w), u2h2(vph2[vb + 3]), a);
      ap[o] = a + __shfl_xor(a, 1);
    }
    float m = ap[0];
#pragma unroll
    for (int o = 1; o < 5; ++o) m = fmaxf(m, ap[o]);
    float es = 0.f, e[5];
#pragma unroll
    for (int o = 0; o < 5; ++o) { e[o] = __expf(ap[o] - m); es += e[o]; }
    const float inv = 1.f / es;
#pragma unroll
    for (int o = 0; o < 5; ++o) {
      const float cc = e[o] * inv;
      h2 hx = u2h2(uv[o].x), hy = u2h2(uv[o].y), hz = u2h2(uv[o].z), hw = u2h2(uv[o].w);
      acc[o][0] += cc * (float)hx[0]; acc[o][1] += cc * (float)hx[1];
      acc[o][2] += cc * (float)hy[0]; acc[o][3] += cc * (float)hy[1];
      acc[o][4] += cc * (float)hz[0]; acc[o][5] += cc * (float)hz[1];
      acc[o][6] += cc * (float)hw[0]; acc[o][7] += cc * (float)hw[1];
    }
  }

#pragma unroll
  for (int off = 2; off <= 32; off <<= 1)
#pragma unroll
    for (int o = 0; o < 5; ++o)
#pragma unroll
      for (int j = 0; j < 8; ++j) acc[o][j] += __shfl_xor(acc[o][j], off);
  const int wid = t >> 6, lane = t & 63;
  if (lane < 2) {
#pragma unroll
    for (int o = 0; o < 5; ++o)
#pragma unroll
      for (int j = 0; j < 8; ++j) red[wid][lane][o * 8 + j] = acc[o][j];
  }
  __syncthreads();

  if (t < 80) {
    const int o = t >> 4, d = t & 15, hh = d >> 3, dl = d & 7;
    const int c = o * 8 + dl;
    float s = red[0][hh][c] + red[1][hh][c] + red[2][hh][c] + red[3][hh][c];
    float sq = s * s;
    sq += __shfl_xor(sq, 1);
    sq += __shfl_xor(sq, 2);
    sq += __shfl_xor(sq, 4);
    sq += __shfl_xor(sq, 8);
    const float scale = sq / (1.f + sq) / sqrtf(sq + 1e-8f);
    const float vn = s * scale;
    if (MODE == 1) {
      vsum_out[(size_t)bl * 80 + t] = v0r + vn;
    } else {
      out[5 * BSZ + (size_t)b * 80 + t] = vn;
      float vv = vn * vn;
      vv += __shfl_xor(vv, 1);
      vv += __shfl_xor(vv, 2);
      vv += __shfl_xor(vv, 4);
      vv += __shfl_xor(vv, 8);
      if ((t & 15) == 0) out[(size_t)b * 5 + o] = sqrtf(vv);
    }
  }
}

// =====================================================================
extern "C" void kernel_launch(void* const* d_in, const int* in_sizes, int n_in,
                              void* d_out, int out_size, void* d_ws, size_t ws_size,
                              hipStream_t stream) {
  const float* x     = (const float*)d_in[0];
  const float* W1    = (const float*)d_in[1];
  const float* b1    = (const float*)d_in[2];
  const float* convW = (const float*)d_in[3];
  const float* convB = (const float*)d_in[4];
  const float* Wr    = (const float*)d_in[5];
  float* out = (float*)d_out;

  char* base = (char*)d_ws;
  size_t off = 0;
  auto alloc = [&](size_t bytes) { size_t o = off; off = (off + bytes + 255) & ~(size_t)255; return o; };
  // persistent (live across routing phase)
  const size_t o_wrh  = alloc((size_t)NCAP * 640 * 2);       // 0.66 MB fp16
  const size_t o_u    = alloc((size_t)BSZ * 4096 * 2);       // 8.4 MB fp16
  const size_t o_s0q  = alloc((size_t)8 * BSZ * 80 * 4);     // 2.6 MB f32
  const size_t o_vsum = alloc((size_t)BSZ * 80 * 4);         // 0.33 MB f32
  // pool: phase 1-2 buffers, later reused for u_hat
  const size_t o_pool = off;
  size_t poff = o_pool;
  auto palloc = [&](size_t bytes) { size_t o = poff; poff = (poff + bytes + 255) & ~(size_t)255; return o; };
  const size_t o_ht  = palloc((size_t)BSZ * PROJ * 2);       // 18.9 MB bf16
  const size_t o_w1t = palloc((size_t)PROJ * INDIM * 2);     // 14.2 MB bf16
  const size_t o_xb  = palloc((size_t)BSZ * INDIM * 2);      // 1.6 MB bf16
  const size_t o_wt2 = palloc((size_t)256 * K2 * 2);         // 1.2 MB bf16
  const size_t o_pb1 = palloc((size_t)PROJ * 4);             // 36 KB f32

  unsigned short* ht   = (unsigned short*)(base + o_ht);
  unsigned short* w1t  = (unsigned short*)(base + o_w1t);
  unsigned short* xb   = (unsigned short*)(base + o_xb);
  unsigned short* wt2  = (unsigned short*)(base + o_wt2);
  float*          pb1  = (float*)(base + o_pb1);
  unsigned short* wrh  = (unsigned short*)(base + o_wrh);
  unsigned short* u    = (unsigned short*)(base + o_u);
  float*          s0q  = (float*)(base + o_s0q);
  float*          vsum = (float*)(base + o_vsum);
  unsigned short* uhat = (unsigned short*)(base + o_pool);   // aliases dead phase-1/2 buffers

  prep_small<<<(PREP_TOTAL + 255) / 256, 256, 0, stream>>>(
      x, xb, Wr, (__half2*)wrh, convW, wt2, b1, pb1);
  transpose_w1_perm<<<dim3(PROJ / 32, INDIM / 32), 256, 0, stream>>>(W1, w1t);

  // ht = relu(x @ W1 + b1) in [b][sp][c] layout — 128x128/BK=64
  mfma_gemm_bk64<<<dim3(PROJ / 128, BSZ / 128), 256, 0, stream>>>(
      xb, w1t, pb1, ht, BSZ, PROJ, INDIM);

  // conv + squash fused, 128x128/BK=64 implicit im2col
  conv_gemm_sq128<<<dim3(2, 128), 256, 0, stream>>>(ht, wt2, convB, u);

  // routing: R8 structure (uhat materialize + 2 streaming passes)
  const size_t pool_sz = ws_size > o_pool ? ws_size - o_pool : 0;
  int CB = 1024;
  while (CB > 16 && (size_t)CB * 512 * 80 * 2 > pool_sz) CB >>= 1;
  for (int b0 = 0; b0 < BSZ; b0 += CB) {
    uhat_gemm<<<dim3(CB / 16, 8), 512, 0, stream>>>(u, wrh, uhat, s0q, b0, CB);
    route_pass<1><<<CB, 256, 0, stream>>>(uhat, s0q, nullptr, vsum, out, b0, CB);
    route_pass<2><<<CB, 256, 0, stream>>>(uhat, nullptr, vsum, nullptr, out, b0, CB);
  }
}

// Round 12
// 152.393 us; speedup vs baseline: 1.0302x; 1.0302x over previous
//
#include <hip/hip_runtime.h>
#include <hip/hip_fp16.h>

#define BSZ   1024
#define INDIM 768
#define PROJ  9216     // 256*6*6
#define NCAP  512
#define NCLS  5
#define K2    2304     // conv GEMM K = 9 taps * 256 ic

typedef __bf16    bf16x8 __attribute__((ext_vector_type(8)));
typedef _Float16  f16x8  __attribute__((ext_vector_type(8)));
typedef float     f32x4  __attribute__((ext_vector_type(4)));
typedef _Float16  h2     __attribute__((ext_vector_type(2)));

static __device__ __forceinline__ unsigned short f2bf(float f) {
  unsigned int x = __float_as_uint(f);
  return (unsigned short)((x + 0x7fffu + ((x >> 16) & 1u)) >> 16);
}
static __device__ __forceinline__ unsigned short f2h(float f) {
  return __builtin_bit_cast(unsigned short, (_Float16)f);
}

#if defined(__has_builtin)
#if __has_builtin(__builtin_amdgcn_fdot2)
#define HAVE_FDOT2 1
#endif
#endif
static __device__ __forceinline__ float fdot2(h2 a, h2 b, float c) {
#ifdef HAVE_FDOT2
  return __builtin_amdgcn_fdot2(a, b, c, false);
#else
  return c + (float)a[0] * (float)b[0] + (float)a[1] * (float)b[1];
#endif
}
static __device__ __forceinline__ h2 u2h2(unsigned int u) {
  return __builtin_bit_cast(h2, u);
}

// global -> LDS direct (16B per lane)
static __device__ __forceinline__ void gload16(const void* g, void* l) {
  auto gp = reinterpret_cast<const unsigned int __attribute__((address_space(1)))*>(
      (unsigned long long)g);
  auto lp = reinterpret_cast<unsigned int __attribute__((address_space(3)))*>(
      (unsigned long long)l);
  __builtin_amdgcn_global_load_lds(gp, lp, 16, 0, 0);
}

// =====================================================================
// mfma_gemm_bk64: 128x128 tile, BK=64 (kept from R11 — measured faster)
// =====================================================================
__global__ __launch_bounds__(256) void mfma_gemm_bk64(
    const unsigned short* __restrict__ A,   // [M][K] bf16
    const unsigned short* __restrict__ Bt,  // [N][K] bf16
    const float* __restrict__ bias,         // [N]
    unsigned short* __restrict__ Cout,      // [M][N] bf16
    int M, int N, int K) {
  __shared__ __align__(16) unsigned short smem[32768];
  const int t    = threadIdx.x;
  const int bn   = blockIdx.x * 128;
  const int bm   = blockIdx.y * 128;
  const int lane = t & 63, wid = t >> 6;
  const int wm   = (wid >> 1) * 64;
  const int wn   = (wid & 1) * 64;
  const int l15  = lane & 15, kb = lane >> 4;

  const unsigned short* asrc[4];
  const unsigned short* bsrc[4];
#pragma unroll
  for (int cc = 0; cc < 4; ++cc) {
    const int c = t + cc * 256;
    const int row = c >> 3, seg = c & 7;
    const int sk = (seg ^ (row & 7)) << 3;
    asrc[cc] = A  + (size_t)(bm + row) * K + sk;
    bsrc[cc] = Bt + (size_t)(bn + row) * K + sk;
  }

  int aoff[4][2], boff[4][2];
#pragma unroll
  for (int i = 0; i < 4; ++i)
#pragma unroll
    for (int kk = 0; kk < 2; ++kk) {
      const int ra = wm + i * 16 + l15, sa = kk * 4 + kb;
      aoff[i][kk] = ra * 64 + ((sa ^ (ra & 7)) << 3);
      const int rb = wn + i * 16 + l15;
      boff[i][kk] = 8192 + rb * 64 + ((sa ^ (rb & 7)) << 3);
    }

  f32x4 acc[4][4];
#pragma unroll
  for (int i = 0; i < 4; ++i)
#pragma unroll
    for (int j = 0; j < 4; ++j)
#pragma unroll
      for (int q = 0; q < 4; ++q) acc[i][j][q] = 0.f;

  const int nk = K >> 6;
  auto stage = [&](int ks, int buf) {
    const int ko = ks << 6;
    unsigned short* sb = &smem[buf * 16384];
#pragma unroll
    for (int cc = 0; cc < 4; ++cc) {
      gload16(asrc[cc] + ko, sb + (t + cc * 256) * 8);
      gload16(bsrc[cc] + ko, sb + 8192 + (t + cc * 256) * 8);
    }
  };

  stage(0, 0);
  __syncthreads();

  int buf = 0;
  for (int ks = 0; ks < nk; ++ks) {
    if (ks + 1 < nk) stage(ks + 1, buf ^ 1);
    const unsigned short* base = &smem[buf * 16384];
    bf16x8 af[4][2], bfr[4][2];
#pragma unroll
    for (int i = 0; i < 4; ++i)
#pragma unroll
      for (int kk = 0; kk < 2; ++kk) {
        af[i][kk]  = *(const bf16x8*)(base + aoff[i][kk]);
        bfr[i][kk] = *(const bf16x8*)(base + boff[i][kk]);
      }
#pragma unroll
    for (int kk = 0; kk < 2; ++kk)
#pragma unroll
      for (int i = 0; i < 4; ++i)
#pragma unroll
        for (int j = 0; j < 4; ++j)
          acc[i][j] = __builtin_amdgcn_mfma_f32_16x16x32_bf16(af[i][kk], bfr[j][kk], acc[i][j], 0, 0, 0);
    __syncthreads();
    buf ^= 1;
  }

#pragma unroll
  for (int j = 0; j < 4; ++j) {
    const int col = bn + wn + j * 16 + l15;
    const float bv = bias[col];
#pragma unroll
    for (int i = 0; i < 4; ++i)
#pragma unroll
      for (int q = 0; q < 4; ++q) {
        const int row = bm + wm + i * 16 + kb * 4 + q;
        Cout[(size_t)row * N + col] = f2bf(fmaxf(acc[i][j][q] + bv, 0.f));
      }
  }
}

// =====================================================================
// conv_gemm_sq (R8 verbatim — measured best: 64x128, BK=64, 24KB LDS)
// =====================================================================
__global__ __launch_bounds__(256) void conv_gemm_sq(
    const unsigned short* __restrict__ ht,   // [1024][36][256] bf16
    const unsigned short* __restrict__ Wt2,  // [256][2304] bf16
    const float* __restrict__ convB,         // [256]
    unsigned short* __restrict__ U) {        // [1024][32][16][8] fp16
  __shared__ __align__(16) unsigned short smem[24576];
  const int t    = threadIdx.x;
  const int bn   = blockIdx.x * 128;
  const int bm   = blockIdx.y * 64;
  const int lane = t & 63, wid = t >> 6;
  const int l15  = lane & 15, kb = lane >> 4;

  const unsigned short* asrc[2];
#pragma unroll
  for (int cc = 0; cc < 2; ++cc) {
    const int c = t + cc * 256;
    const int row = c >> 3, seg = c & 7;
    const int gr = bm + row, b = gr >> 4, p = gr & 15;
    const int spb = (p >> 2) * 6 + (p & 3);
    asrc[cc] = ht + (size_t)b * PROJ + spb * 256 + ((seg ^ (row & 7)) << 3);
  }
  const unsigned short* bsrc[4];
#pragma unroll
  for (int cc = 0; cc < 4; ++cc) {
    const int c = t + cc * 256;
    const int row = c >> 3, seg = c & 7;
    bsrc[cc] = Wt2 + (size_t)(bn + row) * K2 + ((seg ^ (row & 7)) << 3);
  }

  int aoff[4][2], boff[2][2];
#pragma unroll
  for (int i = 0; i < 4; ++i)
#pragma unroll
    for (int kk = 0; kk < 2; ++kk) {
      const int row = i * 16 + l15, seg = kk * 4 + kb;
      aoff[i][kk] = row * 64 + ((seg ^ (row & 7)) << 3);
    }
#pragma unroll
  for (int j = 0; j < 2; ++j)
#pragma unroll
    for (int kk = 0; kk < 2; ++kk) {
      const int row = wid * 32 + j * 16 + l15, seg = kk * 4 + kb;
      boff[j][kk] = 4096 + row * 64 + ((seg ^ (row & 7)) << 3);
    }

  f32x4 acc[4][2];
#pragma unroll
  for (int i = 0; i < 4; ++i)
#pragma unroll
    for (int j = 0; j < 2; ++j)
#pragma unroll
      for (int q = 0; q < 4; ++q) acc[i][j][q] = 0.f;

  auto stage = [&](int ks, int buf) {
    const int tap  = ks >> 2;
    const int aofs = (tap + 3 * (tap / 3)) * 256 + ((ks & 3) << 6);
    const int bofs = ks << 6;
    unsigned short* sb = &smem[buf * 12288];
    gload16(asrc[0] + aofs, sb + t * 8);
    gload16(asrc[1] + aofs, sb + t * 8 + 2048);
    gload16(bsrc[0] + bofs, sb + 4096 + t * 8);
    gload16(bsrc[1] + bofs, sb + 4096 + t * 8 + 2048);
    gload16(bsrc[2] + bofs, sb + 4096 + t * 8 + 4096);
    gload16(bsrc[3] + bofs, sb + 4096 + t * 8 + 6144);
  };

  stage(0, 0);
  __syncthreads();

  int buf = 0;
  for (int ks = 0; ks < 36; ++ks) {
    if (ks + 1 < 36) stage(ks + 1, buf ^ 1);
    const unsigned short* base = &smem[buf * 12288];
    bf16x8 af[4][2], bfr[2][2];
#pragma unroll
    for (int i = 0; i < 4; ++i)
#pragma unroll
      for (int kk = 0; kk < 2; ++kk) af[i][kk] = *(const bf16x8*)(base + aoff[i][kk]);
#pragma unroll
    for (int j = 0; j < 2; ++j)
#pragma unroll
      for (int kk = 0; kk < 2; ++kk) bfr[j][kk] = *(const bf16x8*)(base + boff[j][kk]);
#pragma unroll
    for (int kk = 0; kk < 2; ++kk)
#pragma unroll
      for (int i = 0; i < 4; ++i)
#pragma unroll
        for (int j = 0; j < 2; ++j)
          acc[i][j] = __builtin_amdgcn_mfma_f32_16x16x32_bf16(af[i][kk], bfr[j][kk], acc[i][j], 0, 0, 0);
    __syncthreads();
    buf ^= 1;
  }

#pragma unroll
  for (int j = 0; j < 2; ++j) {
    const int oc  = bn + wid * 32 + j * 16 + l15;
    const int cap = oc >> 3, ii = oc & 7;
    const float bv = convB[oc];
#pragma unroll
    for (int i = 0; i < 4; ++i) {
#pragma unroll
      for (int q = 0; q < 4; ++q) {
        const int row = bm + i * 16 + kb * 4 + q;
        const int b = row >> 4, p = row & 15;
        const float val = acc[i][j][q] + bv;
        float sq = val * val;
        sq += __shfl_xor(sq, 1);
        sq += __shfl_xor(sq, 2);
        sq += __shfl_xor(sq, 4);
        const float scale = sq / (1.f + sq) / sqrtf(sq + 1e-8f);
        U[(size_t)b * 4096 + cap * 128 + p * 8 + ii] = f2h(val * scale);
      }
    }
  }
}

// =====================================================================
// prep_all: W1 transpose tiles (block-granular) + all elementwise preps,
// including wrh_t [80][512][8] fp16 (od-major Wr for the s0 GEMM).
// =====================================================================
#define TP_BLOCKS (288 * 24)            // (PROJ/32) x (INDIM/32)
#define NX_ITEMS (BSZ * INDIM / 4)      // 196608
#define NW_ITEMS (NCAP * 640 / 4)       // 81920
#define NWT_ITEMS (NCAP * 80)           // 40960: (od,n) pairs
#define NC_ITEMS 65536
#define NB_ITEMS PROJ                   // 9216
#define EW_TOTAL (NX_ITEMS + NW_ITEMS + NWT_ITEMS + NC_ITEMS + NB_ITEMS)  // 394240
#define EW_BLOCKS (EW_TOTAL / 256)      // 1540

__global__ __launch_bounds__(256) void prep_all(
    const float* __restrict__ W1, unsigned short* __restrict__ w1t,
    const float* __restrict__ x, unsigned short* __restrict__ xb,
    const float* __restrict__ Wr, __half2* __restrict__ wrh,
    unsigned short* __restrict__ wrh_t,
    const float* __restrict__ convW, unsigned short* __restrict__ wt2,
    const float* __restrict__ b1, float* __restrict__ pb1) {
  __shared__ float tile[32][33];
  if (blockIdx.x < TP_BLOCKS) {
    const int tb = blockIdx.x;
    const int n0 = (tb % 288) * 32, k0 = (tb / 288) * 32;
    const int r = threadIdx.x >> 3, c = (threadIdx.x & 7) * 4;
    float4 v = *(const float4*)(W1 + (size_t)(k0 + r) * PROJ + n0 + c);
    tile[r][c] = v.x; tile[r][c + 1] = v.y; tile[r][c + 2] = v.z; tile[r][c + 3] = v.w;
    __syncthreads();
    ushort4 o;
    o.x = f2bf(tile[c + 0][r]); o.y = f2bf(tile[c + 1][r]);
    o.z = f2bf(tile[c + 2][r]); o.w = f2bf(tile[c + 3][r]);
    const int nn = n0 + r;
    const int prow = (nn % 36) * 256 + nn / 36;
    *(ushort4*)(w1t + (size_t)prow * INDIM + k0 + c) = o;
    return;
  }
  const int id = (blockIdx.x - TP_BLOCKS) * 256 + threadIdx.x;
  if (id < NX_ITEMS) {
    float4 v = ((const float4*)x)[id];
    ushort4 o;
    o.x = f2bf(v.x); o.y = f2bf(v.y); o.z = f2bf(v.z); o.w = f2bf(v.w);
    ((ushort4*)xb)[id] = o;
  } else if (id < NX_ITEMS + NW_ITEMS) {
    const int i = id - NX_ITEMS;
    float4 v = ((const float4*)Wr)[i];
    wrh[i * 2]     = __floats2half2_rn(v.x, v.y);
    wrh[i * 2 + 1] = __floats2half2_rn(v.z, v.w);
  } else if (id < NX_ITEMS + NW_ITEMS + NWT_ITEMS) {
    const int i = id - NX_ITEMS - NW_ITEMS;
    const int od = i / NCAP, n = i % NCAP;   // wrh_t[od][n][0..8)
    const float4 a = *(const float4*)(Wr + (size_t)n * 640 + od * 8);
    const float4 b = *(const float4*)(Wr + (size_t)n * 640 + od * 8 + 4);
    __half2 h0 = __floats2half2_rn(a.x, a.y), h1 = __floats2half2_rn(a.z, a.w);
    __half2 h2v = __floats2half2_rn(b.x, b.y), h3 = __floats2half2_rn(b.z, b.w);
    uint4 st = make_uint4(__builtin_bit_cast(unsigned int, h0),
                          __builtin_bit_cast(unsigned int, h1),
                          __builtin_bit_cast(unsigned int, h2v),
                          __builtin_bit_cast(unsigned int, h3));
    *(uint4*)(wrh_t + (size_t)od * 4096 + n * 8) = st;
  } else if (id < NX_ITEMS + NW_ITEMS + NWT_ITEMS + NC_ITEMS) {
    const int i = id - NX_ITEMS - NW_ITEMS - NWT_ITEMS;
    const int oc = i >> 8, ic = i & 255;
    const float* s = convW + (size_t)i * 9;
#pragma unroll
    for (int tap = 0; tap < 9; ++tap)
      wt2[(size_t)oc * K2 + tap * 256 + ic] = f2bf(s[tap]);
  } else if (id < EW_TOTAL) {
    const int n = id - NX_ITEMS - NW_ITEMS - NWT_ITEMS - NC_ITEMS;
    pb1[(n % 36) * 256 + n / 36] = b1[n];
  }
}

// =====================================================================
// s0v0_gemm: s0[b][od] = 0.2 * sum_{n,i} wrh_t[od][n][i] * u[b][n][i]
// via MFMA over K=4096; per-o squash -> v0[1024][80].
// grid (64 b-tiles, 5 o), 256 threads (4 waves, K split 1024 each).
// =====================================================================
__global__ __launch_bounds__(256) void s0v0_gemm(
    const unsigned short* __restrict__ U,      // [1024][4096] fp16
    const unsigned short* __restrict__ WrhT,   // [80][4096] fp16
    float* __restrict__ v0) {                  // [1024][80]
  __shared__ float red[4][16][16];
  __shared__ float sl[16][17];
  __shared__ float scl[16];
  const int bt = blockIdx.x, o = blockIdx.y;
  const int t = threadIdx.x, wid = t >> 6, lane = t & 63;
  const int l15 = lane & 15, kb = lane >> 4;
  const int gb = bt * 16;

  f32x4 acc;
  acc[0] = 0.f; acc[1] = 0.f; acc[2] = 0.f; acc[3] = 0.f;
  const unsigned short* abase = WrhT + (size_t)(o * 16 + l15) * 4096 + kb * 8;
  const unsigned short* bbase = U + (size_t)(gb + l15) * 4096 + kb * 8;
  const int k0b = wid * 1024;
#pragma unroll 4
  for (int k0 = k0b; k0 < k0b + 1024; k0 += 32) {
    const f16x8 av = __builtin_bit_cast(f16x8, *(const uint4*)(abase + k0));
    const f16x8 bv = __builtin_bit_cast(f16x8, *(const uint4*)(bbase + k0));
    acc = __builtin_amdgcn_mfma_f32_16x16x32_f16(av, bv, acc, 0, 0, 0);
  }
#pragma unroll
  for (int q = 0; q < 4; ++q) red[wid][kb * 4 + q][l15] = acc[q];
  __syncthreads();
  const int row = t >> 4, col = t & 15;    // row = d (within o), col = b
  const float s = 0.2f * (red[0][row][col] + red[1][row][col] +
                          red[2][row][col] + red[3][row][col]);
  sl[row][col] = s;
  __syncthreads();
  if (t < 16) {
    float sq = 0.f;
#pragma unroll
    for (int r = 0; r < 16; ++r) { const float xx = sl[r][t]; sq += xx * xx; }
    scl[t] = sq / (1.f + sq) / sqrtf(sq + 1e-8f);
  }
  __syncthreads();
  v0[(size_t)(gb + col) * 80 + o * 16 + row] = s * scl[col];
}

// =====================================================================
// uhat_p1: uhat_gemm fused with routing pass 1. Computes u_hat fragments
// (MFMA), writes them to global, AND computes a1 = u_hat . v0, softmax,
// s1-partials -> sp1[8][1024][80]. Math mirrors verified route_fused<1>.
// grid (CB/16, 8), 512 threads.
// =====================================================================
__global__ __launch_bounds__(512) void uhat_p1(
    const unsigned short* __restrict__ U,    // [1024][512][8] fp16
    const unsigned short* __restrict__ Wrh,  // [512][80][8] fp16
    const float* __restrict__ v0,            // [1024][80]
    unsigned short* __restrict__ uhat,       // [CB][512][80] fp16
    float* __restrict__ sp1,                 // [8][1024][80] global-b
    int b0, int CB) {
  __shared__ float sred[8][16][80];  // 40 KB
  const int mt = blockIdx.x, q = blockIdx.y;
  const int t = threadIdx.x, wid = t >> 6, lane = t & 63;
  const int l15 = lane & 15, kb = lane >> 4;
  const int bm = mt * 16;
  const int gb = b0 + bm;

  f32x4 vreg[5];
#pragma unroll
  for (int jn = 0; jn < 5; ++jn)
    vreg[jn] = *(const f32x4*)(v0 + (size_t)(gb + l15) * 80 + jn * 16 + kb * 4);

  f32x4 sacc[5];
#pragma unroll
  for (int jn = 0; jn < 5; ++jn)
#pragma unroll
    for (int qq = 0; qq < 4; ++qq) sacc[jn][qq] = 0.f;

  const uint4 zz = make_uint4(0, 0, 0, 0);
#pragma unroll
  for (int i = 0; i < 8; ++i) {
    const int n = q * 64 + wid * 8 + i;
    uint4 av = zz;
    if (kb == 0) av = *(const uint4*)(U + (size_t)(gb + l15) * 4096 + n * 8);
    const f16x8 uf = __builtin_bit_cast(f16x8, av);
    f32x4 cfr[5];
#pragma unroll
    for (int jn = 0; jn < 5; ++jn) {
      uint4 wv = zz;
      if (kb == 0) wv = *(const uint4*)(Wrh + (size_t)n * 640 + (jn * 16 + l15) * 8);
      f32x4 z;
      z[0] = 0.f; z[1] = 0.f; z[2] = 0.f; z[3] = 0.f;
      cfr[jn] = __builtin_amdgcn_mfma_f32_16x16x32_f16(
          __builtin_bit_cast(f16x8, wv), uf, z, 0, 0, 0);
      ushort4 st;
      st.x = f2h(cfr[jn][0]); st.y = f2h(cfr[jn][1]);
      st.z = f2h(cfr[jn][2]); st.w = f2h(cfr[jn][3]);
      *(ushort4*)(uhat + ((size_t)(bm + l15) * 512 + n) * 80 + jn * 16 + kb * 4) = st;
    }
    // a1[o] = u_hat[b,n,o,:] . v0[b,o,:]  (sum over 16 od = 4 regs + kb groups)
    float a[5];
#pragma unroll
    for (int jn = 0; jn < 5; ++jn) {
      float d = cfr[jn][0] * vreg[jn][0] + cfr[jn][1] * vreg[jn][1] +
                cfr[jn][2] * vreg[jn][2] + cfr[jn][3] * vreg[jn][3];
      d += __shfl_xor(d, 16);
      d += __shfl_xor(d, 32);
      a[jn] = d;
    }
    float m = fmaxf(fmaxf(fmaxf(a[0], a[1]), fmaxf(a[2], a[3])), a[4]);
    float c[5], es = 0.f;
#pragma unroll
    for (int o = 0; o < 5; ++o) { c[o] = __expf(a[o] - m); es += c[o]; }
    const float inv = 1.f / es;
#pragma unroll
    for (int jn = 0; jn < 5; ++jn) {
      const float cc = c[jn] * inv;
#pragma unroll
      for (int qq = 0; qq < 4; ++qq) sacc[jn][qq] += cc * cfr[jn][qq];
    }
  }

#pragma unroll
  for (int jn = 0; jn < 5; ++jn)
#pragma unroll
    for (int qq = 0; qq < 4; ++qq)
      sred[wid][l15][jn * 16 + kb * 4 + qq] = sacc[jn][qq];
  __syncthreads();
#pragma unroll
  for (int k = 0; k < 3; ++k) {
    const int id = t + k * 512;
    if (id < 1280) {
      const int bb = id / 80, od = id % 80;
      float val = 0.f;
#pragma unroll
      for (int w = 0; w < 8; ++w) val += sred[w][bb][od];
      sp1[((size_t)q * BSZ + gb + bb) * 80 + od] = val;
    }
  }
}

// v01 = v0 + per-o squash(sum_g sp1)
__global__ __launch_bounds__(128) void v01_k(
    const float* __restrict__ sp1, const float* __restrict__ v0,
    float* __restrict__ v01, int b0) {
  const int b = b0 + blockIdx.x, t = threadIdx.x;
  if (t < 80) {
    float s = 0.f;
#pragma unroll
    for (int g = 0; g < 8; ++g) s += sp1[((size_t)g * BSZ + b) * 80 + t];
    float sq = s * s;
    sq += __shfl_xor(sq, 1);
    sq += __shfl_xor(sq, 2);
    sq += __shfl_xor(sq, 4);
    sq += __shfl_xor(sq, 8);
    const float scale = sq / (1.f + sq) / sqrtf(sq + 1e-8f);
    v01[(size_t)b * 80 + t] = v0[(size_t)b * 80 + t] + s * scale;
  }
}

// =====================================================================
// route_pass2 (R8's route_pass<2> verbatim): final pass, reads u_hat +
// vsum(=v0+v1), emits class_probs and v.
// =====================================================================
__global__ __launch_bounds__(256) void route_pass2(
    const unsigned short* __restrict__ uhat,  // [CB][512][80] fp16
    const float* __restrict__ vsum_in,        // [1024][80] (global-b)
    float* __restrict__ out, int b0) {
  __shared__ unsigned int vph2[40];
  __shared__ float red[4][2][40];
  const int bl = blockIdx.x;
  const int b  = b0 + bl;
  const int t  = threadIdx.x;

  float v0r = 0.f;
  if (t < 80) {
    v0r = vsum_in[(size_t)b * 80 + t];
    const float vnext = __shfl_down(v0r, 1);
    if ((t & 1) == 0)
      vph2[t >> 1] = __builtin_bit_cast(unsigned int, __floats2half2_rn(v0r, vnext));
  }
  __syncthreads();

  const int p = t >> 1, h = t & 1;
  float acc[5][8];
#pragma unroll
  for (int o = 0; o < 5; ++o)
#pragma unroll
    for (int j = 0; j < 8; ++j) acc[o][j] = 0.f;

  const unsigned short* ub = uhat + (size_t)bl * 40960;
  for (int c4 = 0; c4 < 4; ++c4) {
    const int n = c4 * 128 + p;
    const unsigned short* row = ub + n * 80 + h * 8;
    uint4 uv[5];
#pragma unroll
    for (int o = 0; o < 5; ++o) uv[o] = *(const uint4*)(row + o * 16);
    float ap[5];
#pragma unroll
    for (int o = 0; o < 5; ++o) {
      const int vb = o * 8 + h * 4;
      float a = fdot2(u2h2(uv[o].x), u2h2(vph2[vb]), 0.f);
      a = fdot2(u2h2(uv[o].y), u2h2(vph2[vb + 1]), a);
      a = fdot2(u2h2(uv[o].z), u2h2(vph2[vb + 2]), a);
      a = fdot2(u2h2(uv[o].w), u2h2(vph2[vb + 3]), a);
      ap[o] = a + __shfl_xor(a, 1);
    }
    float m = ap[0];
#pragma unroll
    for (int o = 1; o < 5; ++o) m = fmaxf(m, ap[o]);
    float es = 0.f, e[5];
#pragma unroll
    for (int o = 0; o < 5; ++o) { e[o] = __expf(ap[o] - m); es += e[o]; }
    const float inv = 1.f / es;
#pragma unroll
    for (int o = 0; o < 5; ++o) {
      const float cc = e[o] * inv;
      h2 hx = u2h2(uv[o].x), hy = u2h2(uv[o].y), hz = u2h2(uv[o].z), hw = u2h2(uv[o].w);
      acc[o][0] += cc * (float)hx[0]; acc[o][1] += cc * (float)hx[1];
      acc[o][2] += cc * (float)hy[0]; acc[o][3] += cc * (float)hy[1];
      acc[o][4] += cc * (float)hz[0]; acc[o][5] += cc * (float)hz[1];
      acc[o][6] += cc * (float)hw[0]; acc[o][7] += cc * (float)hw[1];
    }
  }

#pragma unroll
  for (int off = 2; off <= 32; off <<= 1)
#pragma unroll
    for (int o = 0; o < 5; ++o)
#pragma unroll
      for (int j = 0; j < 8; ++j) acc[o][j] += __shfl_xor(acc[o][j], off);
  const int wid = t >> 6, lane = t & 63;
  if (lane < 2) {
#pragma unroll
    for (int o = 0; o < 5; ++o)
#pragma unroll
      for (int j = 0; j < 8; ++j) red[wid][lane][o * 8 + j] = acc[o][j];
  }
  __syncthreads();

  if (t < 80) {
    const int o = t >> 4, d = t & 15, hh = d >> 3, dl = d & 7;
    const int c = o * 8 + dl;
    float s = red[0][hh][c] + red[1][hh][c] + red[2][hh][c] + red[3][hh][c];
    float sq = s * s;
    sq += __shfl_xor(sq, 1);
    sq += __shfl_xor(sq, 2);
    sq += __shfl_xor(sq, 4);
    sq += __shfl_xor(sq, 8);
    const float scale = sq / (1.f + sq) / sqrtf(sq + 1e-8f);
    const float vn = s * scale;
    out[5 * BSZ + (size_t)b * 80 + t] = vn;
    float vv = vn * vn;
    vv += __shfl_xor(vv, 1);
    vv += __shfl_xor(vv, 2);
    vv += __shfl_xor(vv, 4);
    vv += __shfl_xor(vv, 8);
    if ((t & 15) == 0) out[(size_t)b * 5 + o] = sqrtf(vv);
  }
}

// =====================================================================
extern "C" void kernel_launch(void* const* d_in, const int* in_sizes, int n_in,
                              void* d_out, int out_size, void* d_ws, size_t ws_size,
                              hipStream_t stream) {
  const float* x     = (const float*)d_in[0];
  const float* W1    = (const float*)d_in[1];
  const float* b1    = (const float*)d_in[2];
  const float* convW = (const float*)d_in[3];
  const float* convB = (const float*)d_in[4];
  const float* Wr    = (const float*)d_in[5];
  float* out = (float*)d_out;

  char* base = (char*)d_ws;
  size_t off = 0;
  auto alloc = [&](size_t bytes) { size_t o = off; off = (off + bytes + 255) & ~(size_t)255; return o; };
  // persistent (live across routing phase)
  const size_t o_wrh  = alloc((size_t)NCAP * 640 * 2);       // 0.66 MB fp16
  const size_t o_wrt  = alloc((size_t)80 * 4096 * 2);        // 0.66 MB fp16
  const size_t o_u    = alloc((size_t)BSZ * 4096 * 2);       // 8.4 MB fp16
  const size_t o_sp1  = alloc((size_t)8 * BSZ * 80 * 4);     // 2.6 MB f32
  const size_t o_v0   = alloc((size_t)BSZ * 80 * 4);         // 0.33 MB f32
  const size_t o_v01  = alloc((size_t)BSZ * 80 * 4);         // 0.33 MB f32
  // pool: phase 1-2 buffers, later reused for u_hat
  const size_t o_pool = off;
  size_t poff = o_pool;
  auto palloc = [&](size_t bytes) { size_t o = poff; poff = (poff + bytes + 255) & ~(size_t)255; return o; };
  const size_t o_ht  = palloc((size_t)BSZ * PROJ * 2);       // 18.9 MB bf16
  const size_t o_w1t = palloc((size_t)PROJ * INDIM * 2);     // 14.2 MB bf16
  const size_t o_xb  = palloc((size_t)BSZ * INDIM * 2);      // 1.6 MB bf16
  const size_t o_wt2 = palloc((size_t)256 * K2 * 2);         // 1.2 MB bf16
  const size_t o_pb1 = palloc((size_t)PROJ * 4);             // 36 KB f32

  unsigned short* ht   = (unsigned short*)(base + o_ht);
  unsigned short* w1t  = (unsigned short*)(base + o_w1t);
  unsigned short* xb   = (unsigned short*)(base + o_xb);
  unsigned short* wt2  = (unsigned short*)(base + o_wt2);
  float*          pb1  = (float*)(base + o_pb1);
  unsigned short* wrh  = (unsigned short*)(base + o_wrh);
  unsigned short* wrt  = (unsigned short*)(base + o_wrt);
  unsigned short* u    = (unsigned short*)(base + o_u);
  float*          sp1  = (float*)(base + o_sp1);
  float*          v0   = (float*)(base + o_v0);
  float*          v01  = (float*)(base + o_v01);
  unsigned short* uhat = (unsigned short*)(base + o_pool);   // aliases dead buffers

  prep_all<<<TP_BLOCKS + EW_BLOCKS, 256, 0, stream>>>(
      W1, w1t, x, xb, Wr, (__half2*)wrh, wrt, convW, wt2, b1, pb1);

  // ht = relu(x @ W1 + b1) in [b][sp][c] layout — 128x128/BK=64
  mfma_gemm_bk64<<<dim3(PROJ / 128, BSZ / 128), 256, 0, stream>>>(
      xb, w1t, pb1, ht, BSZ, PROJ, INDIM);

  // conv + squash fused (64x128 BK=64 — measured best)
  conv_gemm_sq<<<dim3(2, 256), 256, 0, stream>>>(ht, wt2, convB, u);

  // v0 directly from u (iter-0 softmax is uniform)
  s0v0_gemm<<<dim3(BSZ / 16, 5), 256, 0, stream>>>(u, wrt, v0);

  // routing: uhat+pass1 fused, then v01, then final pass
  const size_t pool_sz = ws_size > o_pool ? ws_size - o_pool : 0;
  int CB = 1024;
  while (CB > 16 && (size_t)CB * 512 * 80 * 2 > pool_sz) CB >>= 1;
  for (int b0 = 0; b0 < BSZ; b0 += CB) {
    uhat_p1<<<dim3(CB / 16, 8), 512, 0, stream>>>(u, wrh, v0, uhat, sp1, b0, CB);
    v01_k<<<CB, 128, 0, stream>>>(sp1, v0, v01, b0);
    route_pass2<<<CB, 256, 0, stream>>>(uhat, v01, out, b0);
  }
}